// Round 2
// baseline (38.595 us; speedup 1.0000x reference)
//
#include <hip/hip_runtime.h>
#include <math.h>

#define N_ 16
#define P_ 2048
#define K_ 512
#define H_ 256
#define W_ 256
#define ZTHRESH_ 2.0f

// ---------------------------------------------------------------------------
// Kernel A: one flat grid doing four independent jobs:
//   [0, N*P)            gather uv at pts -> uvp
//   [N*P, +N*K)         solve 2x2 line intersection -> Y  (pinv==inv a.e.)
//   [+N*K, +N*K)        zero wcnt/hcnt
//   [+N_, )             zero per-n completion counters
// ---------------------------------------------------------------------------
__global__ __launch_bounds__(256) void kA(
    const float* __restrict__ uv_img, const int* __restrict__ pts,
    const int* __restrict__ pair, float* __restrict__ Y,
    float* __restrict__ uvp, int* __restrict__ wcnt, int* __restrict__ hcnt,
    int* __restrict__ done) {
  int id = blockIdx.x * 256 + threadIdx.x;
  if (id < N_ * P_) {
    int n = id >> 11, p = id & (P_ - 1);
    int2 c = ((const int2*)pts)[n * P_ + p];
    const float* base = uv_img + (size_t)n * 2 * H_ * W_;
    float2 g;
    g.x = base[c.x * W_ + c.y];
    g.y = base[H_ * W_ + c.x * W_ + c.y];
    ((float2*)uvp)[n * P_ + p] = g;
    return;
  }
  id -= N_ * P_;
  if (id < N_ * K_) {
    int n = id >> 9, k = id & (K_ - 1);
    int2 pr = ((const int2*)pair)[n * K_ + k];
    int2 p0 = ((const int2*)pts)[n * P_ + pr.x];
    int2 p1 = ((const int2*)pts)[n * P_ + pr.y];
    const float* base = uv_img + (size_t)n * 2 * H_ * W_;
    float u00 = base[p0.x * W_ + p0.y];            // uv0 ch0
    float u01 = base[H_ * W_ + p0.x * W_ + p0.y];  // uv0 ch1
    float u10 = base[p1.x * W_ + p1.y];            // uv1 ch0
    float u11 = base[H_ * W_ + p1.x * W_ + p1.y];  // uv1 ch1
    float B0 = (float)(p1.x - p0.x);
    float B1 = (float)(p1.y - p0.y);
    // A = [[u00, -u10], [u01, -u11]]; X = A^-1 B by Cramer.
    float det = u10 * u01 - u00 * u11;
    float x0 = (u10 * B1 - B0 * u11) / det;
    float2 y;
    y.x = x0 * u00 + (float)p0.x;
    y.y = x0 * u01 + (float)p0.y;
    ((float2*)Y)[n * K_ + k] = y;
    return;
  }
  id -= N_ * K_;
  if (id < N_ * K_) {
    wcnt[id] = 0;
    hcnt[id] = 0;
    return;
  }
  id -= N_ * K_;
  if (id < N_) done[id] = 0;
}

// ---------------------------------------------------------------------------
// Kernel B: 272 blocks x 256 threads.
//   blocks [0,256): vote counting — (n, ktile, ptile); ptile of 256 staged in
//                   LDS (broadcast reads); atomicAdd partial counts.
//   blocks [256,272): per-n mean/std (ddof=1) over K -> bad flags.
// Each block "arrives" at done[n] (ACQ_REL, agent scope); the 17th arriver
// performs the final weighted reduction for its n and writes out[n].
// sign(dot(d/||d||, uv)) == sign(dot(d, uv)) incl. d==0 / NaN cases.
// ---------------------------------------------------------------------------
__global__ __launch_bounds__(256) void kB(
    const int* __restrict__ pts, const float* __restrict__ Y,
    const float* __restrict__ uvp, int* __restrict__ bad,
    int* __restrict__ wcnt, int* __restrict__ hcnt, int* __restrict__ done,
    float* __restrict__ out) {
  int b = blockIdx.x, tid = threadIdx.x;
  __shared__ float4 sf[256];  // {pty_f, ptx_f, u, v}
  __shared__ int2 si[256];    // {pty, ptx}
  __shared__ float red[4][3];
  __shared__ float m0s, m1s, sd0s, sd1s;
  __shared__ int s_old;
  int wave = tid >> 6, lane = tid & 63;
  int n;

  if (b < 256) {
    // ---- vote path ----
    n = b >> 4;
    int kt = (b >> 3) & 1, pt = b & 7;
    int p = pt * 256 + tid;
    int2 pc = ((const int2*)pts)[n * P_ + p];
    float2 uc = ((const float2*)uvp)[n * P_ + p];
    sf[tid] = make_float4((float)pc.x, (float)pc.y, uc.x, uc.y);
    si[tid] = pc;
    __syncthreads();

    int k = kt * 256 + tid;
    float2 y = ((const float2*)Y)[n * K_ + k];
    int iy0 = (int)y.x, iy1 = (int)y.y;
    int cnt = 0, hm = 0;
#pragma unroll 4
    for (int i = 0; i < 256; i++) {
      float4 f = sf[i];
      int2 ii = si[i];
      float d0 = y.x - f.x;
      float d1 = y.y - f.y;
      float dot = d0 * f.z + d1 * f.w;
      cnt += (dot > 0.f) ? 1 : 0;
      hm += ((iy0 == ii.x) & (iy1 == ii.y)) ? 1 : 0;
    }
    atomicAdd(&wcnt[n * K_ + k], cnt);
    atomicAdd(&hcnt[n * K_ + k], hm);
  } else {
    // ---- stats path: 2 k per thread ----
    n = b - 256;
    float2 ya = ((const float2*)Y)[n * K_ + tid];
    float2 yb = ((const float2*)Y)[n * K_ + tid + 256];
    float a0 = ya.x + yb.x, a1 = ya.y + yb.y;
    for (int off = 32; off >= 1; off >>= 1) {
      a0 += __shfl_down(a0, off);
      a1 += __shfl_down(a1, off);
    }
    if (lane == 0) { red[wave][0] = a0; red[wave][1] = a1; }
    __syncthreads();
    if (tid == 0) {
      float t0 = red[0][0] + red[1][0] + red[2][0] + red[3][0];
      float t1 = red[0][1] + red[1][1] + red[2][1] + red[3][1];
      m0s = t0 / (float)K_;
      m1s = t1 / (float)K_;
    }
    __syncthreads();
    float m0 = m0s, m1 = m1s;
    float ea0 = ya.x - m0, ea1 = ya.y - m1;
    float eb0 = yb.x - m0, eb1 = yb.y - m1;
    a0 = ea0 * ea0 + eb0 * eb0;
    a1 = ea1 * ea1 + eb1 * eb1;
    for (int off = 32; off >= 1; off >>= 1) {
      a0 += __shfl_down(a0, off);
      a1 += __shfl_down(a1, off);
    }
    __syncthreads();
    if (lane == 0) { red[wave][0] = a0; red[wave][1] = a1; }
    __syncthreads();
    if (tid == 0) {
      float t0 = red[0][0] + red[1][0] + red[2][0] + red[3][0];
      float t1 = red[0][1] + red[1][1] + red[2][1] + red[3][1];
      sd0s = sqrtf(t0 / (float)(K_ - 1));
      sd1s = sqrtf(t1 / (float)(K_ - 1));
    }
    __syncthreads();
    float sd0 = sd0s, sd1 = sd1s;
    int bda = (fabsf(ea0 / sd0) > ZTHRESH_) | (fabsf(ea1 / sd1) > ZTHRESH_) |
              (ya.x != ya.x) | (ya.y != ya.y);
    int bdb = (fabsf(eb0 / sd0) > ZTHRESH_) | (fabsf(eb1 / sd1) > ZTHRESH_) |
              (yb.x != yb.x) | (yb.y != yb.y);
    bad[n * K_ + tid] = bda;
    bad[n * K_ + tid + 256] = bdb;
  }

  // ---- arrive: release our writes, count up; 17th arriver finalizes n ----
  __threadfence();
  __syncthreads();
  if (tid == 0)
    s_old = __hip_atomic_fetch_add(&done[n], 1, __ATOMIC_ACQ_REL,
                                   __HIP_MEMORY_SCOPE_AGENT);
  __syncthreads();
  if (s_old == 16) {
    float sw = 0.f, s0 = 0.f, s1 = 0.f;
    for (int kk = tid; kk < K_; kk += 256) {
      float2 y = ((const float2*)Y)[n * K_ + kk];
      int bd = __hip_atomic_load(&bad[n * K_ + kk], __ATOMIC_RELAXED,
                                 __HIP_MEMORY_SCOPE_AGENT);
      int wc = __hip_atomic_load(&wcnt[n * K_ + kk], __ATOMIC_RELAXED,
                                 __HIP_MEMORY_SCOPE_AGENT);
      int hc = __hip_atomic_load(&hcnt[n * K_ + kk], __ATOMIC_RELAXED,
                                 __HIP_MEMORY_SCOPE_AGENT);
      float w = (float)wc * ((hc == 1) ? 5.0f : 1.0f);  // MULT
      if (bd) w = 0.f;
      sw += w;
      s0 += w * (bd ? 0.f : y.x);
      s1 += w * (bd ? 0.f : y.y);
    }
    for (int off = 32; off >= 1; off >>= 1) {
      sw += __shfl_down(sw, off);
      s0 += __shfl_down(s0, off);
      s1 += __shfl_down(s1, off);
    }
    __syncthreads();
    if (lane == 0) { red[wave][0] = sw; red[wave][1] = s0; red[wave][2] = s1; }
    __syncthreads();
    if (tid == 0) {
      float tw = red[0][0] + red[1][0] + red[2][0] + red[3][0];
      float t0 = red[0][1] + red[1][1] + red[2][1] + red[3][1];
      float t1 = red[0][2] + red[1][2] + red[2][2] + red[3][2];
      float den = fmaxf(tw, 1.0f);
      out[n * 2 + 0] = t1 / den;  // pixel_xy reverses coord order
      out[n * 2 + 1] = t0 / den;
    }
  }
}

extern "C" void kernel_launch(void* const* d_in, const int* in_sizes, int n_in,
                              void* d_out, int out_size, void* d_ws,
                              size_t ws_size, hipStream_t stream) {
  const float* uv_img = (const float*)d_in[0];
  const int* pts = (const int*)d_in[1];
  const int* pair = (const int*)d_in[2];
  float* out = (float*)d_out;

  float* Y = (float*)d_ws;               // N*K*2
  float* uvp = Y + N_ * K_ * 2;          // N*P*2
  int* bad = (int*)(uvp + N_ * P_ * 2);  // N*K
  int* wcnt = bad + N_ * K_;             // N*K
  int* hcnt = wcnt + N_ * K_;            // N*K
  int* done = hcnt + N_ * K_;            // N

  int itemsA = N_ * P_ + N_ * K_ + N_ * K_ + N_;
  hipLaunchKernelGGL(kA, dim3((itemsA + 255) / 256), dim3(256), 0, stream,
                     uv_img, pts, pair, Y, uvp, wcnt, hcnt, done);
  hipLaunchKernelGGL(kB, dim3(272), dim3(256), 0, stream, pts, Y, uvp, bad,
                     wcnt, hcnt, done, out);
}

// Round 3
// 28.732 us; speedup vs baseline: 1.3433x; 1.3433x over previous
//
#include <hip/hip_runtime.h>
#include <math.h>

#define N_ 16
#define P_ 2048
#define K_ 512
#define H_ 256
#define W_ 256
#define HW_ (H_ * W_)
#define ZT_ 2.0f

// ---------------------------------------------------------------------------
// Kernel 1: 256 blocks (b = n*16 + kt) x 512 threads.
// Each block owns n = b>>4 and the 32 k's [kt*32, kt*32+32), and processes ALL
// P points for them -> complete vote counts in registers. No atomics, no
// cross-block state, nothing needs pre-zeroing.
//   phase 1: solve all 512 Y's for this n (1 per thread; redundant x16 blocks)
//   phase 2: per-n mean/std (ddof=1) + bad flags (redundant, deterministic)
//   phase 3: vote loop, 8 LDS tiles of 256 points; 16 lanes share one k
//   phase 4: width-16 then block reduction -> partial[b] = {Sw, Sw*y0, Sw*y1}
// sign(dot(d/||d||, uv)) == sign(dot(d, uv)) incl. d==0 / inf / NaN cases
// (inf/NaN Y rows are 'bad' -> weight forced to 0, so their count is moot).
// ---------------------------------------------------------------------------
__global__ __launch_bounds__(512) void hough_main(
    const float* __restrict__ uv_img, const int* __restrict__ pts,
    const int* __restrict__ pair, float4* __restrict__ partial) {
  int b = blockIdx.x;
  int n = b >> 4, kt = b & 15;
  int tid = threadIdx.x;
  int lane = tid & 63, wave = tid >> 6;

  __shared__ float2 Ys[K_];
  __shared__ float4 sf[256];  // {pty_f, ptx_f, u, v}
  __shared__ int2 si[256];    // {pty, ptx}
  __shared__ unsigned char badf[K_];
  __shared__ float red[8][3];
  __shared__ float bc[4];  // mean0, mean1, std0, std1

  const int2* pts2 = (const int2*)pts + n * P_;
  const float* base = uv_img + (size_t)n * 2 * HW_;

  // ---- phase 1: Y solve (Cramer; pinv == inv a.e.) ----
  {
    int2 pr = ((const int2*)pair)[n * K_ + tid];
    int2 p0 = pts2[pr.x];
    int2 p1 = pts2[pr.y];
    float u00 = base[p0.x * W_ + p0.y];
    float u01 = base[HW_ + p0.x * W_ + p0.y];
    float u10 = base[p1.x * W_ + p1.y];
    float u11 = base[HW_ + p1.x * W_ + p1.y];
    float B0 = (float)(p1.x - p0.x);
    float B1 = (float)(p1.y - p0.y);
    float det = u10 * u01 - u00 * u11;
    float x0 = (u10 * B1 - B0 * u11) / det;
    Ys[tid] = make_float2(x0 * u00 + (float)p0.x, x0 * u01 + (float)p0.y);
  }
  __syncthreads();

  // ---- phase 2: stats (NaN propagates, matching jnp) ----
  float2 y = Ys[tid];
  float a0 = y.x, a1 = y.y;
  for (int off = 32; off >= 1; off >>= 1) {
    a0 += __shfl_down(a0, off);
    a1 += __shfl_down(a1, off);
  }
  if (lane == 0) { red[wave][0] = a0; red[wave][1] = a1; }
  __syncthreads();
  if (tid == 0) {
    float t0 = 0.f, t1 = 0.f;
    for (int i = 0; i < 8; i++) { t0 += red[i][0]; t1 += red[i][1]; }
    bc[0] = t0 / (float)K_;
    bc[1] = t1 / (float)K_;
  }
  __syncthreads();
  float m0 = bc[0], m1 = bc[1];
  float e0 = y.x - m0, e1 = y.y - m1;
  a0 = e0 * e0;
  a1 = e1 * e1;
  for (int off = 32; off >= 1; off >>= 1) {
    a0 += __shfl_down(a0, off);
    a1 += __shfl_down(a1, off);
  }
  if (lane == 0) { red[wave][0] = a0; red[wave][1] = a1; }
  __syncthreads();
  if (tid == 0) {
    float t0 = 0.f, t1 = 0.f;
    for (int i = 0; i < 8; i++) { t0 += red[i][0]; t1 += red[i][1]; }
    bc[2] = sqrtf(t0 / (float)(K_ - 1));
    bc[3] = sqrtf(t1 / (float)(K_ - 1));
  }
  __syncthreads();
  float sd0 = bc[2], sd1 = bc[3];
  int bd = (fabsf(e0 / sd0) > ZT_) | (fabsf(e1 / sd1) > ZT_) |
           (y.x != y.x) | (y.y != y.y);
  badf[tid] = (unsigned char)bd;
  // badf is read in phase 4, after multiple __syncthreads in phase 3.

  // ---- phase 3: votes. my k: 16 lanes (pl) share it ----
  int k = kt * 32 + (tid >> 4);
  int pl = tid & 15;
  float2 yk = Ys[k];
  int iy0 = (int)yk.x, iy1 = (int)yk.y;
  int cnt = 0, hm = 0;

  for (int t = 0; t < 8; t++) {
    __syncthreads();  // protect previous tile's readers
    int pp = tid & 255, ch = tid >> 8;
    int p = t * 256 + pp;
    int2 pc = pts2[p];
    float g = base[ch * HW_ + pc.x * W_ + pc.y];
    ((float*)&sf[pp])[2 + ch] = g;
    if (ch == 0) {
      ((float*)&sf[pp])[0] = (float)pc.x;
      ((float*)&sf[pp])[1] = (float)pc.y;
      si[pp] = pc;
    }
    __syncthreads();
#pragma unroll 4
    for (int i = 0; i < 16; i++) {
      int idx = pl + 16 * i;
      float4 f = sf[idx];
      int2 ii = si[idx];
      float d0 = yk.x - f.x;
      float d1 = yk.y - f.y;
      float dot = d0 * f.z + d1 * f.w;
      cnt += (dot > 0.f) ? 1 : 0;
      hm += ((iy0 == ii.x) & (iy1 == ii.y)) ? 1 : 0;
    }
  }

  // ---- phase 4: reduce. width-16 groups are wave-aligned ----
  for (int off = 8; off >= 1; off >>= 1) {
    cnt += __shfl_down(cnt, off);
    hm += __shfl_down(hm, off);
  }
  float w = 0.f, s0 = 0.f, s1 = 0.f;
  if (pl == 0) {
    if (badf[k]) {
      w = 0.f;  // and keep s0=s1=0 (never multiply a possibly-NaN yk)
    } else {
      w = (float)cnt * ((hm == 1) ? 5.0f : 1.0f);  // MULT
      s0 = w * yk.x;
      s1 = w * yk.y;
    }
  }
  for (int off = 32; off >= 1; off >>= 1) {
    w += __shfl_down(w, off);
    s0 += __shfl_down(s0, off);
    s1 += __shfl_down(s1, off);
  }
  __syncthreads();  // red[] reuse
  if (lane == 0) { red[wave][0] = w; red[wave][1] = s0; red[wave][2] = s1; }
  __syncthreads();
  if (tid == 0) {
    float tw = 0.f, t0 = 0.f, t1 = 0.f;
    for (int i = 0; i < 8; i++) {
      tw += red[i][0];
      t0 += red[i][1];
      t1 += red[i][2];
    }
    partial[b] = make_float4(tw, t0, t1, 0.f);
  }
}

// ---------------------------------------------------------------------------
// Kernel 2: 1 block x 256 threads. Deterministic fixed-order combine of the
// 256 per-block partials (16 per n), divide, write out (reversed coords).
// Same-stream kernel boundary provides agent-scope release/acquire, so the
// plain stores from kernel 1 are visible here without fences.
// ---------------------------------------------------------------------------
__global__ __launch_bounds__(256) void hough_final(
    const float4* __restrict__ partial, float* __restrict__ out) {
  int tid = threadIdx.x;  // tid = n*16 + kt
  float4 p = partial[tid];
  float sw = p.x, s0 = p.y, s1 = p.z;
  for (int off = 8; off >= 1; off >>= 1) {
    sw += __shfl_down(sw, off);
    s0 += __shfl_down(s0, off);
    s1 += __shfl_down(s1, off);
  }
  if ((tid & 15) == 0) {
    int n = tid >> 4;
    float den = fmaxf(sw, 1.0f);
    out[n * 2 + 0] = s1 / den;  // pixel_xy reverses coord order
    out[n * 2 + 1] = s0 / den;
  }
}

extern "C" void kernel_launch(void* const* d_in, const int* in_sizes, int n_in,
                              void* d_out, int out_size, void* d_ws,
                              size_t ws_size, hipStream_t stream) {
  const float* uv_img = (const float*)d_in[0];
  const int* pts = (const int*)d_in[1];
  const int* pair = (const int*)d_in[2];
  float* out = (float*)d_out;
  float4* partial = (float4*)d_ws;  // 256 x float4, fully overwritten each call

  hipLaunchKernelGGL(hough_main, dim3(256), dim3(512), 0, stream, uv_img, pts,
                     pair, partial);
  hipLaunchKernelGGL(hough_final, dim3(1), dim3(256), 0, stream, partial, out);
}

// Round 4
// 26.458 us; speedup vs baseline: 1.4588x; 1.0860x over previous
//
#include <hip/hip_runtime.h>
#include <math.h>

#define N_ 16
#define P_ 2048
#define K_ 512
#define H_ 256
#define W_ 256
#define HW_ (H_ * W_)
#define ZT_ 2.0f
#define GBLK_ 128  // gather blocks in K1 (128*256 == N_*P_)
#define KB_ 32     // vote blocks per n in K2
#define KPB_ 16    // k's per vote block (KB_*KPB_ == K_)

// ---------------------------------------------------------------------------
// K1: precompute (144 blocks x 256 threads).
//  blocks [0,128): gather uv at all N*P pts -> uvp (scattered reads ONCE).
//  blocks [128,144): per-n (n = b-128): solve all 512 Y (Cramer; pinv==inv
//  a.e.), per-n mean/std (ddof=1) -> bad flags; zero done[n].
// ---------------------------------------------------------------------------
__global__ __launch_bounds__(256) void k_pre(
    const float* __restrict__ uv_img, const int* __restrict__ pts,
    const int* __restrict__ pair, float2* __restrict__ uvp,
    float2* __restrict__ Yg, int* __restrict__ bad, int* __restrict__ done) {
  int tid = threadIdx.x;
  if (blockIdx.x < GBLK_) {
    int id = blockIdx.x * 256 + tid;  // id == n*P_ + p
    int2 c = ((const int2*)pts)[id];
    const float* base = uv_img + (size_t)(id >> 11) * 2 * HW_;
    int o = c.x * W_ + c.y;
    uvp[id] = make_float2(base[o], base[HW_ + o]);
    return;
  }
  int n = blockIdx.x - GBLK_;
  if (tid == 0) done[n] = 0;
  const int2* pts2 = (const int2*)pts + n * P_;
  const int2* pr2 = (const int2*)pair + n * K_;
  const float* base = uv_img + (size_t)n * 2 * HW_;

  float2 ya, yb;
#pragma unroll
  for (int h = 0; h < 2; h++) {
    int k = tid + h * 256;
    int2 pr = pr2[k];
    int2 p0 = pts2[pr.x];
    int2 p1 = pts2[pr.y];
    float u00 = base[p0.x * W_ + p0.y];
    float u01 = base[HW_ + p0.x * W_ + p0.y];
    float u10 = base[p1.x * W_ + p1.y];
    float u11 = base[HW_ + p1.x * W_ + p1.y];
    float B0 = (float)(p1.x - p0.x);
    float B1 = (float)(p1.y - p0.y);
    float det = u10 * u01 - u00 * u11;
    float x0 = (u10 * B1 - B0 * u11) / det;
    float2 y = make_float2(x0 * u00 + (float)p0.x, x0 * u01 + (float)p0.y);
    if (h == 0) ya = y; else yb = y;
    Yg[n * K_ + k] = y;
  }

  // stats over the 512 Y of this n (2 per thread); NaN propagates like jnp.
  __shared__ float red[4][2];
  __shared__ float bc[4];
  int wave = tid >> 6, lane = tid & 63;
  float a0 = ya.x + yb.x, a1 = ya.y + yb.y;
  for (int off = 32; off >= 1; off >>= 1) {
    a0 += __shfl_down(a0, off);
    a1 += __shfl_down(a1, off);
  }
  if (lane == 0) { red[wave][0] = a0; red[wave][1] = a1; }
  __syncthreads();
  if (tid == 0) {
    float t0 = red[0][0] + red[1][0] + red[2][0] + red[3][0];
    float t1 = red[0][1] + red[1][1] + red[2][1] + red[3][1];
    bc[0] = t0 / (float)K_;
    bc[1] = t1 / (float)K_;
  }
  __syncthreads();
  float m0 = bc[0], m1 = bc[1];
  float ea0 = ya.x - m0, ea1 = ya.y - m1;
  float eb0 = yb.x - m0, eb1 = yb.y - m1;
  a0 = ea0 * ea0 + eb0 * eb0;
  a1 = ea1 * ea1 + eb1 * eb1;
  for (int off = 32; off >= 1; off >>= 1) {
    a0 += __shfl_down(a0, off);
    a1 += __shfl_down(a1, off);
  }
  if (lane == 0) { red[wave][0] = a0; red[wave][1] = a1; }
  __syncthreads();
  if (tid == 0) {
    float t0 = red[0][0] + red[1][0] + red[2][0] + red[3][0];
    float t1 = red[0][1] + red[1][1] + red[2][1] + red[3][1];
    bc[2] = sqrtf(t0 / (float)(K_ - 1));
    bc[3] = sqrtf(t1 / (float)(K_ - 1));
  }
  __syncthreads();
  float sd0 = bc[2], sd1 = bc[3];
  int bda = (fabsf(ea0 / sd0) > ZT_) | (fabsf(ea1 / sd1) > ZT_) |
            (ya.x != ya.x) | (ya.y != ya.y);
  int bdb = (fabsf(eb0 / sd0) > ZT_) | (fabsf(eb1 / sd1) > ZT_) |
            (yb.x != yb.x) | (yb.y != yb.y);
  bad[n * K_ + tid] = bda;
  bad[n * K_ + tid + 256] = bdb;
}

// ---------------------------------------------------------------------------
// K2: votes (512 blocks x 256 threads). b -> n = b>>5, ktile = b&31 (16 k's).
// Stage all 2048 points of n once in LDS as {u, v, c = p.uv, packed_p}; then
// 128 uninterrupted iterations (16 lanes share one k, lane pl covers points
// pl+16i). sign(yk.uv - c) == sign((yk-p).uv) == reference's normalized dot
// (positive-norm division preserves sign; bad rows get w=0 anyway).
// Ends with one release-RMW per block; last arriver per n combines the 32
// partials in fixed order (deterministic) and writes out[n].
// ---------------------------------------------------------------------------
__global__ __launch_bounds__(256) void k_vote(
    const int* __restrict__ pts, const float2* __restrict__ uvp,
    const float2* __restrict__ Yg, const int* __restrict__ bad,
    float* __restrict__ pw, float* __restrict__ ps0, float* __restrict__ ps1,
    int* __restrict__ done, float* __restrict__ out) {
  int b = blockIdx.x, tid = threadIdx.x;
  int n = b >> 5, kt = b & (KB_ - 1);
  __shared__ float4 sf[P_];
  __shared__ float red[4][3];
  __shared__ int sflag;
  const int2* pts2 = (const int2*)pts + n * P_;
  const float2* uvn = uvp + n * P_;

#pragma unroll
  for (int j = 0; j < 8; j++) {
    int p = j * 256 + tid;
    int2 pc = pts2[p];
    float2 uc = uvn[p];
    float c = (float)pc.x * uc.x + (float)pc.y * uc.y;
    int pk = (pc.x << 8) | pc.y;
    sf[p] = make_float4(uc.x, uc.y, c, __int_as_float(pk));
  }

  int k = kt * KPB_ + (tid >> 4);
  int pl = tid & 15;
  float2 yk = Yg[n * K_ + k];
  int iy0 = (int)yk.x, iy1 = (int)yk.y;
  int mk = (((unsigned)iy0 < 256u) & ((unsigned)iy1 < 256u))
               ? ((iy0 << 8) | iy1) : -1;
  __syncthreads();

  int cnt = 0, hm = 0;
#pragma unroll 8
  for (int i = 0; i < P_ / 16; i++) {
    float4 f = sf[pl + (i << 4)];
    float dot = fmaf(yk.x, f.x, fmaf(yk.y, f.y, -f.z));
    cnt += (dot > 0.f) ? 1 : 0;
    hm += (__float_as_int(f.w) == mk) ? 1 : 0;
  }

  // reduce 16 lanes -> pl==0 holds totals for k
  for (int off = 8; off >= 1; off >>= 1) {
    cnt += __shfl_down(cnt, off, 16);
    hm += __shfl_down(hm, off, 16);
  }
  float w = 0.f, s0 = 0.f, s1 = 0.f;
  if (pl == 0 && !bad[n * K_ + k]) {
    w = (float)cnt * ((hm == 1) ? 5.0f : 1.0f);  // MULT
    s0 = w * yk.x;
    s1 = w * yk.y;
  }
  for (int off = 32; off >= 1; off >>= 1) {
    w += __shfl_down(w, off);
    s0 += __shfl_down(s0, off);
    s1 += __shfl_down(s1, off);
  }
  int wave = tid >> 6, lane = tid & 63;
  if (lane == 0) { red[wave][0] = w; red[wave][1] = s0; red[wave][2] = s1; }
  __syncthreads();
  if (tid == 0) {
    float tw = red[0][0] + red[1][0] + red[2][0] + red[3][0];
    float t0 = red[0][1] + red[1][1] + red[2][1] + red[3][1];
    float t1 = red[0][2] + red[1][2] + red[2][2] + red[3][2];
    pw[b] = tw;
    ps0[b] = t0;
    ps1[b] = t1;
    // release our partial, count arrivals for this n
    int old = __hip_atomic_fetch_add(&done[n], 1, __ATOMIC_ACQ_REL,
                                     __HIP_MEMORY_SCOPE_AGENT);
    sflag = (old == KB_ - 1);
  }
  __syncthreads();
  if (sflag && tid < KB_) {
    int i = (n << 5) + tid;
    float fw = __hip_atomic_load(&pw[i], __ATOMIC_RELAXED,
                                 __HIP_MEMORY_SCOPE_AGENT);
    float f0 = __hip_atomic_load(&ps0[i], __ATOMIC_RELAXED,
                                 __HIP_MEMORY_SCOPE_AGENT);
    float f1 = __hip_atomic_load(&ps1[i], __ATOMIC_RELAXED,
                                 __HIP_MEMORY_SCOPE_AGENT);
    for (int off = 16; off >= 1; off >>= 1) {
      fw += __shfl_down(fw, off, 32);
      f0 += __shfl_down(f0, off, 32);
      f1 += __shfl_down(f1, off, 32);
    }
    if (tid == 0) {
      float den = fmaxf(fw, 1.0f);
      out[n * 2 + 0] = f1 / den;  // pixel_xy reverses coord order
      out[n * 2 + 1] = f0 / den;
    }
  }
}

extern "C" void kernel_launch(void* const* d_in, const int* in_sizes, int n_in,
                              void* d_out, int out_size, void* d_ws,
                              size_t ws_size, hipStream_t stream) {
  const float* uv_img = (const float*)d_in[0];
  const int* pts = (const int*)d_in[1];
  const int* pair = (const int*)d_in[2];
  float* out = (float*)d_out;

  float2* uvp = (float2*)d_ws;             // N*P float2
  float2* Yg = uvp + N_ * P_;              // N*K float2
  int* bad = (int*)(Yg + N_ * K_);         // N*K int
  float* pw = (float*)(bad + N_ * K_);     // N*KB_
  float* ps0 = pw + N_ * KB_;              // N*KB_
  float* ps1 = ps0 + N_ * KB_;             // N*KB_
  int* done = (int*)(ps1 + N_ * KB_);      // N_

  hipLaunchKernelGGL(k_pre, dim3(GBLK_ + N_), dim3(256), 0, stream, uv_img,
                     pts, pair, uvp, Yg, bad, done);
  hipLaunchKernelGGL(k_vote, dim3(N_ * KB_), dim3(256), 0, stream, pts, uvp,
                     Yg, bad, pw, ps0, ps1, done, out);
}